// Round 1
// baseline (368.047 us; speedup 1.0000x reference)
//
#include <hip/hip_runtime.h>
#include <math.h>

// Problem constants (from reference setup_inputs / GRID construction)
#define B_DIM  2
#define NCAM   6
#define D_DIM  48
#define H_DIM  28
#define W_DIM  60
#define C_DIM  64
#define X_DIM  128
#define Y_DIM  128
#define Z_DIM  4
#define NCELL  (B_DIM * X_DIM * Y_DIM)   // 32768 BEV cells
#define FR_CAM ((size_t)D_DIM * H_DIM * W_DIM * C_DIM)

// ---------------------------------------------------------------------------
// v2 of the fused kernel. Timing evidence says dur_us = 2x ~150us harness
// re-poison fills + ~13us kernel (kernel absent from rocprof top-5, so
// <147us). This round attacks the kernel-internal costs:
//   1. Gauss-Jordan kept bit-identical but with a STATICALLY-indexed
//      branchless row swap -> A[4][8] stays in registers (the old
//      A[p][jj] runtime-pivot swap forced the array into scratch; ~300
//      dependent scratch accesses per block x 8192 blocks).
//   2. 4 consecutive x-cells per wave, gathered with a 4-way interleaved
//      mask loop (4x memory-level parallelism for hot waves), stored as
//      ONE float4 per lane -> 16B contiguous instead of 64 scattered
//      4B stores (16x fewer cache-line touches on the TA).
// Per-cell FP accumulation order, geometry expressions and pivot decisions
// are unchanged -> bit-identical output expected (absmax stays 0.0078125).
// ---------------------------------------------------------------------------

__device__ __forceinline__ void gather_one(float& acc, int pk, float kfx, float kfy, float kfz,
                                           const float* __restrict__ fbase) {
    int kn = (pk >> 24) & 0xff;
    int zi = ((pk >> 16) & 0xff) - 1;
    int yi = ((pk >> 8)  & 0xff) - 1;
    int xi = (pk & 0xff) - 1;
    float wx[2] = {1.0f - kfx, kfx};
    float wy[2] = {1.0f - kfy, kfy};
    float wz[2] = {1.0f - kfz, kfz};
    const float* fb = fbase + (size_t)kn * FR_CAM;
#pragma unroll
    for (int dz = 0; dz < 2; dz++) {
        int zz = zi + dz;
        if (zz < 0 || zz > D_DIM - 1) continue;
#pragma unroll
        for (int dy = 0; dy < 2; dy++) {
            int yy = yi + dy;
            if (yy < 0 || yy > H_DIM - 1) continue;
            float wzy = wz[dz] * wy[dy];
#pragma unroll
            for (int dx = 0; dx < 2; dx++) {
                int xx = xi + dx;
                if (xx < 0 || xx > W_DIM - 1) continue;
                float w = wzy * wx[dx];
                acc += w * fb[(((size_t)zz * H_DIM + yy) * W_DIM + xx) * C_DIM];
            }
        }
    }
}

__global__ __launch_bounds__(256) void frustum_to_bev_fused(
        const float* __restrict__ frustum,
        const float* __restrict__ intr,
        const float* __restrict__ l2s,
        float* __restrict__ out) {
    __shared__ float Ms[B_DIM * NCAM * 12];

    int t = threadIdx.x;
    if (t < B_DIM * NCAM) {
        float A[4][8];
        const float* L = l2s + t * 16;
#pragma unroll
        for (int i = 0; i < 4; i++) {
#pragma unroll
            for (int jj = 0; jj < 4; jj++) A[i][jj] = L[i * 4 + jj];
#pragma unroll
            for (int jj = 0; jj < 4; jj++) A[i][4 + jj] = (i == jj) ? 1.0f : 0.0f;
        }
#pragma unroll
        for (int col = 0; col < 4; col++) {
            int p = col;
            float mx = fabsf(A[col][col]);
#pragma unroll
            for (int r = col + 1; r < 4; r++) {
                float v = fabsf(A[r][col]);
                if (v > mx) { mx = v; p = r; }
            }
            // Branchless pivot swap: exactly one r==p swaps (or none if
            // p==col). Identical values to the physical swap, but all array
            // indices are compile-time -> A stays in VGPRs (no scratch).
#pragma unroll
            for (int r = col + 1; r < 4; r++) {
                bool sw = (p == r);
#pragma unroll
                for (int jj = 0; jj < 8; jj++) {
                    float a = A[col][jj], bsw = A[r][jj];
                    A[col][jj] = sw ? bsw : a;
                    A[r][jj]   = sw ? a : bsw;
                }
            }
            float inv = 1.0f / A[col][col];
#pragma unroll
            for (int jj = 0; jj < 8; jj++) A[col][jj] *= inv;
#pragma unroll
            for (int r = 0; r < 4; r++) {
                if (r == col) continue;
                float f = A[r][col];
#pragma unroll
                for (int jj = 0; jj < 8; jj++) A[r][jj] -= f * A[col][jj];
            }
        }
        const float* K = intr + t * 9;
#pragma unroll
        for (int r = 0; r < 3; r++) {
#pragma unroll
            for (int c = 0; c < 4; c++) {
                float s = 0.0f;
#pragma unroll
                for (int k = 0; k < 3; k++) s += K[r * 3 + k] * A[k][4 + c];
                Ms[t * 12 + r * 4 + c] = s;
            }
        }
    }
    __syncthreads();

    int wg   = (blockIdx.x << 2) | (t >> 6);   // wave id, 0..8191
    int lane = t & 63;                         // channel c in gather phase
    int cellbase = wg << 2;                    // 4 consecutive cells per wave
    int b  = cellbase >> 14;
    int y  = (cellbase >> 7) & 127;
    int x0 = cellbase & 127;                   // multiple of 4, never crosses y

    float py = 0.75f * (float)y - 47.625f;

    // lane j in [0,48): q = cell parity within pass, s = sample (n,z)
    int j = (lane < 48) ? lane : 0;
    int q = (j >= 24) ? 1 : 0;
    int s = j - 24 * q;
    int n = s >> 2;
    int z = s & 3;
    float pz = 2.0f * (float)z - 3.0f;         // {-3,-1,1,3}

    const float* mm = &Ms[(b * NCAM + n) * 12];
    float M0 = mm[0], M1 = mm[1], M2 = mm[2],  M3  = mm[3];
    float M4 = mm[4], M5 = mm[5], M6 = mm[6],  M7  = mm[7];
    float M8 = mm[8], M9 = mm[9], M10 = mm[10], M11 = mm[11];

    int pA, pB;
    float fxA, fyA, fzA, fxB, fyB, fzB;
    unsigned mk0, mk1, mk2, mk3;

    // ---- geometry pass 0: cells x0+0 (lanes 0..23) and x0+1 (lanes 24..47)
    {
        int xc = x0 + q;
        float px = 0.75f * (float)xc - 47.625f;
        float uu = M0 * px + M1 * py + M2  * pz + M3;
        float vv = M4 * px + M5 * py + M6  * pz + M7;
        float dd = M8 * px + M9 * py + M10 * pz + M11;
        float ix = (uu / dd) * (59.0f / 60.0f);
        float iy = (vv / dd) * (27.0f / 28.0f);
        float iz = (dd - 2.0f) * (47.0f / 48.0f);
        bool valid = (lane < 48) &&
                     (ix > -1.0f) && (ix < 60.0f) &&
                     (iy > -1.0f) && (iy < 28.0f) &&
                     (iz > -1.0f) && (iz < 48.0f);   // NaN (dd~0) -> invalid
        float xf = floorf(ix), yf = floorf(iy), zf = floorf(iz);
        fxA = ix - xf; fyA = iy - yf; fzA = iz - zf;
        pA = (n << 24) | ((((int)zf + 1) & 0xff) << 16)
           | ((((int)yf + 1) & 0xff) << 8) | (((int)xf + 1) & 0xff);
        unsigned long long bl = __ballot(valid);
        mk0 = (unsigned)(bl & 0xffffffULL);
        mk1 = (unsigned)((bl >> 24) & 0xffffffULL);
    }
    // ---- geometry pass 1: cells x0+2 and x0+3
    {
        int xc = x0 + 2 + q;
        float px = 0.75f * (float)xc - 47.625f;
        float uu = M0 * px + M1 * py + M2  * pz + M3;
        float vv = M4 * px + M5 * py + M6  * pz + M7;
        float dd = M8 * px + M9 * py + M10 * pz + M11;
        float ix = (uu / dd) * (59.0f / 60.0f);
        float iy = (vv / dd) * (27.0f / 28.0f);
        float iz = (dd - 2.0f) * (47.0f / 48.0f);
        bool valid = (lane < 48) &&
                     (ix > -1.0f) && (ix < 60.0f) &&
                     (iy > -1.0f) && (iy < 28.0f) &&
                     (iz > -1.0f) && (iz < 48.0f);
        float xf = floorf(ix), yf = floorf(iy), zf = floorf(iz);
        fxB = ix - xf; fyB = iy - yf; fzB = iz - zf;
        pB = (n << 24) | ((((int)zf + 1) & 0xff) << 16)
           | ((((int)yf + 1) & 0xff) << 8) | (((int)xf + 1) & 0xff);
        unsigned long long bl = __ballot(valid);
        mk2 = (unsigned)(bl & 0xffffffULL);
        mk3 = (unsigned)((bl >> 24) & 0xffffffULL);
    }

    // ---- gather: 4 cells interleaved (4x MLP); per-cell bit order is the
    // same ascending (n,z) order as the validated kernel -> identical FP sums.
    float acc0 = 0.0f, acc1 = 0.0f, acc2 = 0.0f, acc3 = 0.0f;
    const float* fbase = frustum + (size_t)b * NCAM * FR_CAM + lane;

    while (mk0 | mk1 | mk2 | mk3) {
        if (mk0) {
            int k = __ffs(mk0) - 1; mk0 &= mk0 - 1;
            int   pk  = __shfl(pA, k);
            float a = __shfl(fxA, k), bb = __shfl(fyA, k), cc = __shfl(fzA, k);
            gather_one(acc0, pk, a, bb, cc, fbase);
        }
        if (mk1) {
            int k = __ffs(mk1) + 23; mk1 &= mk1 - 1;   // source lane = bit + 24
            int   pk  = __shfl(pA, k);
            float a = __shfl(fxA, k), bb = __shfl(fyA, k), cc = __shfl(fzA, k);
            gather_one(acc1, pk, a, bb, cc, fbase);
        }
        if (mk2) {
            int k = __ffs(mk2) - 1; mk2 &= mk2 - 1;
            int   pk  = __shfl(pB, k);
            float a = __shfl(fxB, k), bb = __shfl(fyB, k), cc = __shfl(fzB, k);
            gather_one(acc2, pk, a, bb, cc, fbase);
        }
        if (mk3) {
            int k = __ffs(mk3) + 23; mk3 &= mk3 - 1;
            int   pk  = __shfl(pB, k);
            float a = __shfl(fxB, k), bb = __shfl(fyB, k), cc = __shfl(fzB, k);
            gather_one(acc3, pk, a, bb, cc, fbase);
        }
    }

    // out[b][c][y][x0..x0+3], c = lane: one 16B-contiguous float4 per lane
    float4 v4 = make_float4(acc0, acc1, acc2, acc3);
    *reinterpret_cast<float4*>(out + ((((size_t)b * C_DIM + lane) * Y_DIM + y) * X_DIM + x0)) = v4;
}

extern "C" void kernel_launch(void* const* d_in, const int* in_sizes, int n_in,
                              void* d_out, int out_size, void* d_ws, size_t ws_size,
                              hipStream_t stream) {
    const float* frustum = (const float*)d_in[0];  // [2,6,48,28,60,64] f32
    const float* intr    = (const float*)d_in[1];  // [2,6,3,3] f32
    const float* l2s     = (const float*)d_in[2];  // [2,6,4,4] f32
    float* out = (float*)d_out;                    // [2,64,128,128] f32

    // 32768 cells, 16 cells per 256-thread block (4 waves x 4 cells), 1 launch
    frustum_to_bev_fused<<<NCELL / 16, 256, 0, stream>>>(frustum, intr, l2s, out);
}

// Round 4
// 288.596 us; speedup vs baseline: 1.2753x; 1.2753x over previous
//
#include <hip/hip_runtime.h>
#include <math.h>

// Problem constants (from reference setup_inputs / GRID construction)
#define B_DIM  2
#define NCAM   6
#define D_DIM  48
#define H_DIM  28
#define W_DIM  60
#define C_DIM  64
#define X_DIM  128
#define Y_DIM  128
#define Z_DIM  4
#define NCELL  (B_DIM * X_DIM * Y_DIM)   // 32768 BEV cells
#define FR_CAM ((size_t)D_DIM * H_DIM * W_DIM * C_DIM)

// ---------------------------------------------------------------------------
// v3, third submission (rounds 2 and 3 both died to MI355X container
// acquisition flakes — kernel never executed; audited clean for hang/OOB).
//
// Post-mortem of v2 (+53us): work is extremely imbalanced — only cells near
// the grid center project into any camera, so kernel time is dominated by
// the TAIL of a few hot waves (~24 serial gather iterations each). v2's
// 4-cells-per-wave stacked 4 hot cells onto one wave and serialized 4
// shfl/vmcnt round-trips per iteration -> tail x4-8. Reverted.
//
// v3 = v1 mapping (1 cell/wave) + three surgical changes:
//   1. Register-only Gauss-Jordan (validated in v2, bit-identical).
//   2. Branch-free clamped corner gather + manual depth-2 software pipeline:
//      issue sample k+1's loads before consuming sample k. Only `acc` chains
//      across iterations, so load latency overlaps -> hot-wave tail ~halved+.
//      OOB corners contribute w=0.0 exactly (adding +/-0.0 never changes the
//      sum's bits) and use clamped in-bounds addresses.
//   3. Store via LDS transpose: block's 4 waves are 4 consecutive x, so
//      stores become 16B-contiguous quads (4x fewer line touches).
// Per-cell FP accumulation order identical to the validated kernel.
// ---------------------------------------------------------------------------

__device__ __forceinline__ void gather_issue(float* v, int pk,
                                             const float* __restrict__ fbase) {
    int kn = (pk >> 24) & 0xff;
    int zi = ((pk >> 16) & 0xff) - 1;
    int yi = ((pk >> 8)  & 0xff) - 1;
    int xi = (pk & 0xff) - 1;
    const float* fb = fbase + (size_t)kn * FR_CAM;
#pragma unroll
    for (int dz = 0; dz < 2; dz++) {
        int zc = min(max(zi + dz, 0), D_DIM - 1);
#pragma unroll
        for (int dy = 0; dy < 2; dy++) {
            int yc = min(max(yi + dy, 0), H_DIM - 1);
#pragma unroll
            for (int dx = 0; dx < 2; dx++) {
                int xc = min(max(xi + dx, 0), W_DIM - 1);
                v[dz * 4 + dy * 2 + dx] =
                    fb[(((size_t)zc * H_DIM + yc) * W_DIM + xc) * C_DIM];
            }
        }
    }
}

__device__ __forceinline__ void gather_consume(float& acc, const float* v, int pk,
                                               float kfx, float kfy, float kfz) {
    int zi = ((pk >> 16) & 0xff) - 1;
    int yi = ((pk >> 8)  & 0xff) - 1;
    int xi = (pk & 0xff) - 1;
    float wx[2] = {1.0f - kfx, kfx};
    float wy[2] = {1.0f - kfy, kfy};
    float wz[2] = {1.0f - kfz, kfz};
#pragma unroll
    for (int dz = 0; dz < 2; dz++) {
        int zz = zi + dz;
        bool bz = (zz >= 0) && (zz <= D_DIM - 1);
#pragma unroll
        for (int dy = 0; dy < 2; dy++) {
            int yy = yi + dy;
            bool by = (yy >= 0) && (yy <= H_DIM - 1);
            float wzy = wz[dz] * wy[dy];
#pragma unroll
            for (int dx = 0; dx < 2; dx++) {
                int xx = xi + dx;
                bool bx = (xx >= 0) && (xx <= W_DIM - 1);
                // exact same product order as validated kernel: (wz*wy)*wx
                float w = (bz && by && bx) ? (wzy * wx[dx]) : 0.0f;
                acc += w * v[dz * 4 + dy * 2 + dx];
            }
        }
    }
}

__global__ __launch_bounds__(256) void frustum_to_bev_fused(
        const float* __restrict__ frustum,
        const float* __restrict__ intr,
        const float* __restrict__ l2s,
        float* __restrict__ out) {
    __shared__ float Ms[B_DIM * NCAM * 12];
    __shared__ float accs[4][65];   // +1 pad: conflict-light transpose read

    int t = threadIdx.x;
    if (t < B_DIM * NCAM) {
        float A[4][8];
        const float* L = l2s + t * 16;
#pragma unroll
        for (int i = 0; i < 4; i++) {
#pragma unroll
            for (int jj = 0; jj < 4; jj++) A[i][jj] = L[i * 4 + jj];
#pragma unroll
            for (int jj = 0; jj < 4; jj++) A[i][4 + jj] = (i == jj) ? 1.0f : 0.0f;
        }
#pragma unroll
        for (int col = 0; col < 4; col++) {
            int p = col;
            float mx = fabsf(A[col][col]);
#pragma unroll
            for (int r = col + 1; r < 4; r++) {
                float v = fabsf(A[r][col]);
                if (v > mx) { mx = v; p = r; }
            }
            // Branchless pivot swap, statically indexed -> A stays in VGPRs.
            // Same pivot decisions / values as the physical swap (validated v2).
#pragma unroll
            for (int r = col + 1; r < 4; r++) {
                bool sw = (p == r);
#pragma unroll
                for (int jj = 0; jj < 8; jj++) {
                    float a = A[col][jj], bsw = A[r][jj];
                    A[col][jj] = sw ? bsw : a;
                    A[r][jj]   = sw ? a : bsw;
                }
            }
            float inv = 1.0f / A[col][col];
#pragma unroll
            for (int jj = 0; jj < 8; jj++) A[col][jj] *= inv;
#pragma unroll
            for (int r = 0; r < 4; r++) {
                if (r == col) continue;
                float f = A[r][col];
#pragma unroll
                for (int jj = 0; jj < 8; jj++) A[r][jj] -= f * A[col][jj];
            }
        }
        const float* K = intr + t * 9;
#pragma unroll
        for (int r = 0; r < 3; r++) {
#pragma unroll
            for (int c = 0; c < 4; c++) {
                float s = 0.0f;
#pragma unroll
                for (int k = 0; k < 3; k++) s += K[r * 3 + k] * A[k][4 + c];
                Ms[t * 12 + r * 4 + c] = s;
            }
        }
    }
    __syncthreads();

    int wave = (blockIdx.x << 2) | (t >> 6);   // cell id, 0..32767 (as v1)
    int lane = t & 63;                         // channel c in gather phase
    int b = wave >> 14;
    int y = (wave >> 7) & 127;
    int x = wave & 127;

    float px = 0.75f * (float)x - 47.625f;     // voxel-center lidar coords
    float py = 0.75f * (float)y - 47.625f;

    // ---- geometry: lane j in [0,24) owns sample (n=j>>2, z=j&3) ----
    int j  = (lane < NCAM * Z_DIM) ? lane : 0;
    int n  = j >> 2;
    int z  = j & 3;
    const float* m = &Ms[(b * NCAM + n) * 12];
    float pz = 2.0f * (float)z - 3.0f;                    // {-3,-1,1,3}
    float uu = m[0] * px + m[1] * py + m[2]  * pz + m[3];
    float vv = m[4] * px + m[5] * py + m[6]  * pz + m[7];
    float dd = m[8] * px + m[9] * py + m[10] * pz + m[11];

    // identical expressions to the validated kernels (align_corners=True)
    float ix = (uu / dd) * (59.0f / 60.0f);
    float iy = (vv / dd) * (27.0f / 28.0f);
    float iz = (dd - 2.0f) * (47.0f / 48.0f);

    bool valid = (lane < NCAM * Z_DIM) &&
                 (ix > -1.0f) && (ix < 60.0f) &&
                 (iy > -1.0f) && (iy < 28.0f) &&
                 (iz > -1.0f) && (iz < 48.0f);   // NaN (dd~0) fails -> invalid

    float xf = floorf(ix), yf = floorf(iy), zf = floorf(iz);
    float fx = ix - xf, fy = iy - yf, fz = iz - zf;
    int packed = (n << 24) | ((((int)zf + 1) & 0xff) << 16)
               | ((((int)yf + 1) & 0xff) << 8) | (((int)xf + 1) & 0xff);

    unsigned long long mask = __ballot(valid);

    // ---- gather: lanes = channels; valid samples in ascending (n,z) order,
    // depth-2 pipelined (issue k+1's loads before consuming k). ----
    float acc = 0.0f;
    const float* fbase = frustum + (size_t)b * NCAM * FR_CAM + lane;

    if (mask) {
        int k = __ffsll(mask) - 1; mask &= mask - 1;
        int   cpk = __shfl(packed, k);
        float cfx = __shfl(fx, k), cfy = __shfl(fy, k), cfz = __shfl(fz, k);
        float cv[8];
        gather_issue(cv, cpk, fbase);
        while (mask) {
            int k2 = __ffsll(mask) - 1; mask &= mask - 1;
            int   npk = __shfl(packed, k2);
            float nfx = __shfl(fx, k2), nfy = __shfl(fy, k2), nfz = __shfl(fz, k2);
            float nv[8];
            gather_issue(nv, npk, fbase);
            gather_consume(acc, cv, cpk, cfx, cfy, cfz);
            cpk = npk; cfx = nfx; cfy = nfy; cfz = nfz;
#pragma unroll
            for (int i = 0; i < 8; i++) cv[i] = nv[i];
        }
        gather_consume(acc, cv, cpk, cfx, cfy, cfz);
    }

    // ---- store: transpose through LDS so each 4-lane quad writes 16B
    // contiguous at out[b][c][y][x0..x0+3] (block's 4 waves = 4 consecutive x)
    accs[t >> 6][lane] = acc;
    __syncthreads();

    int cellbase = blockIdx.x << 2;
    int bb = cellbase >> 14;
    int yy = (cellbase >> 7) & 127;
    int x0 = cellbase & 127;
    int c  = t >> 2;
    int xi = t & 3;
    out[(((size_t)bb * C_DIM + c) * Y_DIM + yy) * X_DIM + x0 + xi] = accs[xi][c];
}

extern "C" void kernel_launch(void* const* d_in, const int* in_sizes, int n_in,
                              void* d_out, int out_size, void* d_ws, size_t ws_size,
                              hipStream_t stream) {
    const float* frustum = (const float*)d_in[0];  // [2,6,48,28,60,64] f32
    const float* intr    = (const float*)d_in[1];  // [2,6,3,3] f32
    const float* l2s     = (const float*)d_in[2];  // [2,6,4,4] f32
    float* out = (float*)d_out;                    // [2,64,128,128] f32

    // 32768 cells, 1 cell per wave, 4 waves per 256-thread block, 1 launch
    frustum_to_bev_fused<<<NCELL / 4, 256, 0, stream>>>(frustum, intr, l2s, out);
}